// Round 10
// baseline (115.233 us; speedup 1.0000x reference)
//
#include <hip/hip_runtime.h>
#include <cmath>

#define B_N 65536
#define C_N 128
#define D_N 32
#define K_N 10
#define EPS_F 1e-12f
#define SCALE_F (-0.72134752044448169f)   // -0.5 * log2(e)

#define NKK 46                    // 45 live K-steps + 1 zero pad
#define HKK 23                    // steps per K-half (2 halves)
#define CHUNK_F16 4096            // per-step Q chunk: 4ct x 2hl x 64lane x 8 f16 = 8 KB
#define QF_N (NKK * CHUNK_F16)
#define YSTR 33                   // y row stride: (33*l+i)%32 = (l+i)%32 -> conflict-free
#define SY_FLOATS (128 * YSTR + 64)           // 128 rows + zeroed tail
#define SY_BYTES  (SY_FLOATS * 4)             // 17408 B (16-mult)
#define SMEM_BYTES (2 * 8448 * 4)             // 67584: max(sy+ring, 2x scratch)

typedef _Float16 f16x8 __attribute__((ext_vector_type(8)));
typedef float    f32x16 __attribute__((ext_vector_type(16)));

// Step metadata, affine in (window w, row-pair r) order; kk=45 is zero-Q pad.
__device__ __forceinline__ void mdkk(int kk, int& dA, int& e0) {
    if (kk >= 45) { dA = 0; e0 = 0; return; }
    int w = (kk >= 17) + (kk >= 30) + (kk >= 39) + (kk >= 44);
    int off = w == 0 ? 0 : (w == 1 ? 17 : (w == 2 ? 30 : (w == 3 ? 39 : 44)));
    int r = kk - off;
    dA = 2 * r;
    e0 = 2 * r + 8 * w;
}

// ---------------------------------------------------------------------------
// Fused prep (unchanged): block = cluster c; packs Q chunks
//   QF[kk*4096 + ct*1024 + hl*512 + (half*32 + (c&31))*8 + j]
// ---------------------------------------------------------------------------
__global__ __launch_bounds__(128) void k_prep(const float* __restrict__ S,
                                              const float* __restrict__ mu,
                                              const int* __restrict__ onehot,
                                              _Float16* __restrict__ QF,
                                              int* __restrict__ cls) {
    const int c = blockIdx.x;
    const int tid = threadIdx.x;
    __shared__ float sSm[D_N];
    __shared__ float st3;

    if (tid < D_N) {
        const float* Sr = S + (size_t)c * (D_N * D_N) + (size_t)tid * D_N;
        const float* mr = mu + (size_t)c * D_N;
        float a0 = 0.f, a1 = 0.f;
#pragma unroll
        for (int e = 0; e < D_N; e += 2) {
            a0 = fmaf(Sr[e + 0], mr[e + 0], a0);
            a1 = fmaf(Sr[e + 1], mr[e + 1], a1);
        }
        sSm[tid] = a0 + a1;
    }
    __syncthreads();
    if (tid == 0) {
        const float* mr = mu + (size_t)c * D_N;
        float a = 0.f;
#pragma unroll
        for (int d = 0; d < D_N; ++d) a = fmaf(mr[d], sSm[d], a);
        st3 = a;
        int cl = 0;
#pragma unroll
        for (int k = 0; k < K_N; ++k)
            if (onehot[c * K_N + k] != 0) cl = k;
        cls[c] = cl;
    }
    __syncthreads();

    if (tid < 2 * NKK) {
        const int kk   = tid >> 1;
        const int half = tid & 1;
        int dA, e0;
        mdkk(kk, dA, e0);
        const int d  = dA + half;
        const int ct = c >> 5;
        const size_t base = (size_t)kk * CHUNK_F16 + ct * 1024
                          + (size_t)(half * 32 + (c & 31)) * 8;
        const float* Sc = S + (size_t)c * (D_N * D_N);
        for (int j = 0; j < 8; ++j) {
            const int e = e0 + j;
            float q = 0.f;
            if (kk < 45 && d <= e && e <= 32) {
                float v;
                if (e < 32)      v = Sc[d * D_N + e] * (d == e ? 1.f : 2.f);
                else if (d < 32) v = -2.f * sSm[d];
                else             v = st3;          // d == e == 32
                q = SCALE_F * v;
            }
            _Float16 h = (_Float16)q;
            QF[base + j]       = h;                         // hi
            QF[base + 512 + j] = (_Float16)(q - (float)h);  // lo
        }
    }
}

// ---------------------------------------------------------------------------
// v8 helpers
// ---------------------------------------------------------------------------
__device__ __forceinline__ void gl_lds16(const void* g, void* l) {
    __builtin_amdgcn_global_load_lds(
        (const __attribute__((address_space(1))) unsigned int*)g,
        (__attribute__((address_space(3))) unsigned int*)l, 16, 0, 0);
}

__device__ __forceinline__ void stage_chunk(const _Float16* __restrict__ QF,
                                            _Float16* __restrict__ dst,
                                            int chunk, int wid, int lane) {
#pragma unroll
    for (int i = 0; i < 2; ++i) {
        const int slot = i * 4 + wid;
        gl_lds16(QF + (size_t)chunk * CHUNK_F16 + slot * 512 + lane * 8,
                 dst + slot * 512);
    }
}

__device__ __forceinline__ void ldy1(const float* sy, int ybase, int hioff,
                                     int kk, float& yd, float (&yw)[8]) {
    int dA, e0;
    mdkk(kk, dA, e0);
    yd = sy[ybase + dA + hioff];
#pragma unroll
    for (int j = 0; j < 8; ++j) yw[j] = sy[ybase + e0 + j];
}

__device__ __forceinline__ void mkphi(float yd, const float (&yw)[8],
                                      f16x8& ph, f16x8& pl) {
#pragma unroll
    for (int j = 0; j < 8; j += 2) {
        float f0 = yd * yw[j], f1 = yd * yw[j + 1];
        auto h2 = __builtin_amdgcn_cvt_pkrtz(f0, f1);
        float r0 = f0 - (float)h2[0];
        float r1 = f1 - (float)h2[1];
        auto l2 = __builtin_amdgcn_cvt_pkrtz(r0, r1);
        ph[j] = h2[0]; ph[j + 1] = h2[1];
        pl[j] = l2[0]; pl[j + 1] = l2[1];
    }
}

// One K-step for 64 rows (2 b-groups) x 128 c (4 c-tiles), 3 fp16 sections.
__device__ __forceinline__ void step2(const _Float16* __restrict__ buf, int lane,
                                      float yd0, const float (&yw0)[8],
                                      float yd1, const float (&yw1)[8],
                                      f32x16 (&acc0)[4], f32x16 (&acc1)[4]) {
    const f16x8* qbv = (const f16x8*)buf;
    f16x8 qh[4], ql[4];
#pragma unroll
    for (int ct = 0; ct < 4; ++ct) {
        qh[ct] = qbv[ct * 128 + lane];
        ql[ct] = qbv[ct * 128 + 64 + lane];
    }
    f16x8 ph0, pl0, ph1, pl1;
    mkphi(yd0, yw0, ph0, pl0);
    mkphi(yd1, yw1, ph1, pl1);
    __builtin_amdgcn_s_setprio(1);
#pragma unroll
    for (int ct = 0; ct < 4; ++ct)
        acc0[ct] = __builtin_amdgcn_mfma_f32_32x32x16_f16(qh[ct], ph0, acc0[ct], 0, 0, 0);
#pragma unroll
    for (int ct = 0; ct < 4; ++ct)
        acc1[ct] = __builtin_amdgcn_mfma_f32_32x32x16_f16(qh[ct], ph1, acc1[ct], 0, 0, 0);
#pragma unroll
    for (int ct = 0; ct < 4; ++ct)
        acc0[ct] = __builtin_amdgcn_mfma_f32_32x32x16_f16(ql[ct], ph0, acc0[ct], 0, 0, 0);
#pragma unroll
    for (int ct = 0; ct < 4; ++ct)
        acc1[ct] = __builtin_amdgcn_mfma_f32_32x32x16_f16(ql[ct], ph1, acc1[ct], 0, 0, 0);
#pragma unroll
    for (int ct = 0; ct < 4; ++ct)
        acc0[ct] = __builtin_amdgcn_mfma_f32_32x32x16_f16(qh[ct], pl0, acc0[ct], 0, 0, 0);
#pragma unroll
    for (int ct = 0; ct < 4; ++ct)
        acc1[ct] = __builtin_amdgcn_mfma_f32_32x32x16_f16(qh[ct], pl1, acc1[ct], 0, 0, 0);
    __builtin_amdgcn_s_setprio(0);
}

// ---------------------------------------------------------------------------
// Main v8: Q-amortization + K-split. Block = 128 rows, 4 waves:
// wave = (pair = rows 64*pair.., kh = K-half of 23 steps). Each wave: 64 rows
// (2 b-groups) x all 128 c x its K-half -> Q LDS reads per output HALVED
// (v7's saturated-LDS diagnosis: demand 1186 cyc/step/CU ~ wall 1098).
// New floor: LDS 15.3 us ~ MFMA 14.9 us. Ring: 2 slots per half (4 x 8 KB).
// Per iter: vmcnt(0)[only own stage(t) outstanding, issued one phase ago ->
// ~free]; s_barrier; stage both halves' step t+1; compute. K-halves combined
// post-loop via lane-rotated LDS scratch (reuses sy+ring space); waves kh=0
// run the fused epilogue for both b-groups.
// ---------------------------------------------------------------------------
__global__ __launch_bounds__(256, 2) void k_mainv8(const float* __restrict__ data,
                                                   const _Float16* __restrict__ QF,
                                                   const int* __restrict__ clsp,
                                                   float* __restrict__ out) {
    const int tid  = threadIdx.x;
    const int lane = tid & 63;
    const int wid  = tid >> 6;
    const int pair = wid >> 1;                  // row-pair: 0 -> rows 0-63, 1 -> 64-127
    const int kh   = wid & 1;                   // K-half
    const int col  = lane & 31;
    const bool hi  = lane >= 32;
    const int rbase = blockIdx.x * 128 + pair * 64;

    __shared__ __attribute__((aligned(16))) char smem[SMEM_BYTES];
    __shared__ int lcls[C_N];
    float*    sy = (float*)smem;
    _Float16* qb = (_Float16*)(smem + SY_BYTES);

    if (tid < C_N) lcls[tid] = clsp[tid];
    if (tid < 128) {                            // y row = local row tid
        const float4* p0 = (const float4*)(data + (size_t)(blockIdx.x * 128 + tid) * D_N);
        const int yb = tid * YSTR;
#pragma unroll
        for (int i = 0; i < 8; ++i) {
            float4 v = p0[i];
            sy[yb + 4 * i + 0] = v.x;
            sy[yb + 4 * i + 1] = v.y;
            sy[yb + 4 * i + 2] = v.z;
            sy[yb + 4 * i + 3] = v.w;
        }
        sy[yb + 32] = 1.f;                       // homogeneous slot
    }
    if (tid < 64) sy[128 * YSTR + tid] = 0.f;    // zero tail (row127 window overrun)

    f32x16 acc0[4], acc1[4];
#pragma unroll
    for (int ct = 0; ct < 4; ++ct)
#pragma unroll
        for (int g = 0; g < 16; ++g) { acc0[ct][g] = 0.f; acc1[ct][g] = 0.f; }

    // prologue: stage step-0 chunks of both halves; full drain once
    stage_chunk(QF, qb + 0 * CHUNK_F16, 0,   wid, lane);
    stage_chunk(QF, qb + 2 * CHUNK_F16, HKK, wid, lane);
    __syncthreads();

    const int hioff = hi ? 1 : 0;
    const int yb0 = (pair * 64 + col) * YSTR;
    const int yb1 = yb0 + 32 * YSTR;

#pragma clang loop unroll(disable)
    for (int t = 0; t < HKK; ++t) {
        // own stage(t) is the only outstanding vmem; issued one phase ago
        asm volatile("s_waitcnt vmcnt(0)" ::: "memory");
        __builtin_amdgcn_s_barrier();
        __builtin_amdgcn_sched_barrier(0);
        if (t + 1 < HKK) {                       // stage step t+1, both halves
            stage_chunk(QF, qb + (((t + 1) & 1)) * CHUNK_F16, t + 1, wid, lane);
            stage_chunk(QF, qb + (2 + ((t + 1) & 1)) * CHUNK_F16, HKK + t + 1, wid, lane);
        }
        const int kk = kh * HKK + t;
        float yd0, yw0[8], yd1, yw1[8];
        ldy1(sy, yb0, hioff, kk, yd0, yw0);
        ldy1(sy, yb1, hioff, kk, yd1, yw1);
        step2(qb + (kh * 2 + (t & 1)) * CHUNK_F16, lane, yd0, yw0, yd1, yw1, acc0, acc1);
    }

    // ---------------- K-half combine via LDS scratch ------------------------
    __syncthreads();                             // smem reusable from here
    float* scr = (float*)smem + pair * 8448;     // 64 lanes x 132 floats
    if (kh == 1) {
#pragma unroll
        for (int bg = 0; bg < 2; ++bg) {
            const f32x16* ap = bg ? acc1 : acc0;
#pragma unroll
            for (int ct = 0; ct < 4; ++ct)
#pragma unroll
                for (int gq = 0; gq < 4; ++gq) {
                    const int g4 = bg * 16 + ct * 4 + gq;
                    const int fo = lane * 132 + (((g4 + 2 * lane) & 31) << 2);
                    *(float4*)(scr + fo) = make_float4(ap[ct][4 * gq + 0], ap[ct][4 * gq + 1],
                                                       ap[ct][4 * gq + 2], ap[ct][4 * gq + 3]);
                }
        }
    }
    __syncthreads();
    if (kh != 0) return;                         // writers done (no more barriers)

#pragma unroll
    for (int bg = 0; bg < 2; ++bg) {
        f32x16* ap = bg ? acc1 : acc0;
#pragma unroll
        for (int ct = 0; ct < 4; ++ct)
#pragma unroll
            for (int gq = 0; gq < 4; ++gq) {
                const int g4 = bg * 16 + ct * 4 + gq;
                const int fo = lane * 132 + (((g4 + 2 * lane) & 31) << 2);
                float4 v = *(const float4*)(scr + fo);
                ap[ct][4 * gq + 0] += v.x; ap[ct][4 * gq + 1] += v.y;
                ap[ct][4 * gq + 2] += v.z; ap[ct][4 * gq + 3] += v.w;
            }
    }

    // ---------------- fused finalize (per b-group) ---------------------------
    // C/D layout (HW-verified): col=lane&31 (b), c = ct*32+(g&3)+8*(g>>2)+4*hi
    const float hoff = hi ? 4.f : 0.f;
    const int* lc = lcls + (hi ? 4 : 0);
#pragma unroll
    for (int bg = 0; bg < 2; ++bg) {
        const f32x16* ap = bg ? acc1 : acc0;
        float sum = 0.f, gmax = -1.f, gcf = 0.f;
        float a0 = 0, a1 = 0, a2 = 0, a3 = 0, a4 = 0, a5 = 0, a6 = 0, a7 = 0, a8 = 0, a9 = 0;
#pragma unroll
        for (int ct = 0; ct < 4; ++ct) {
            float psum = 0.f;
#pragma unroll
            for (int g = 0; g < 16; ++g) {
                float v = ap[ct][g];
                float gm;
                asm("v_exp_f32 %0, %1" : "=v"(gm) : "v"(v));   // 2^v = exp(-0.5 d2)
                const int cbase = ct * 32 + (g & 3) + 8 * (g >> 2);
                int cl = lc[cbase];
                psum += gm;
                float cf = (float)cbase + hoff;
                if (gm > gmax) { gmax = gm; gcf = cf; }        // c scanned ascending
                a0 += (cl == 0) ? gm : 0.f;
                a1 += (cl == 1) ? gm : 0.f;
                a2 += (cl == 2) ? gm : 0.f;
                a3 += (cl == 3) ? gm : 0.f;
                a4 += (cl == 4) ? gm : 0.f;
                a5 += (cl == 5) ? gm : 0.f;
                a6 += (cl == 6) ? gm : 0.f;
                a7 += (cl == 7) ? gm : 0.f;
                a8 += (cl == 8) ? gm : 0.f;
                a9 += (cl == 9) ? gm : 0.f;
            }
            sum += psum;
        }

        sum += __shfl_xor(sum, 32, 64);
        {
            float om = __shfl_xor(gmax, 32, 64);
            float oc = __shfl_xor(gcf, 32, 64);
            bool take = (om > gmax) || (om == gmax && oc < gcf);  // first-index tie
            if (take) { gmax = om; gcf = oc; }
        }
        a0 += __shfl_xor(a0, 32, 64);
        a1 += __shfl_xor(a1, 32, 64);
        a2 += __shfl_xor(a2, 32, 64);
        a3 += __shfl_xor(a3, 32, 64);
        a4 += __shfl_xor(a4, 32, 64);
        a5 += __shfl_xor(a5, 32, 64);
        a6 += __shfl_xor(a6, 32, 64);
        a7 += __shfl_xor(a7, 32, 64);
        a8 += __shfl_xor(a8, 32, 64);
        a9 += __shfl_xor(a9, 32, 64);

        if (!hi) {
            const int b = rbase + bg * 32 + col;
            float inv = 1.0f / (sum + EPS_F);
            float ls[K_N] = {a0 * inv, a1 * inv, a2 * inv, a3 * inv, a4 * inv,
                             a5 * inv, a6 * inv, a7 * inv, a8 * inv, a9 * inv};
            float best = -1.f;
            int bk = 0;
#pragma unroll
            for (int k = 0; k < K_N; ++k)
                if (ls[k] > best) { best = ls[k]; bk = k; }
            float2* o2 = (float2*)(out + (size_t)b * K_N);
#pragma unroll
            for (int k2 = 0; k2 < K_N / 2; ++k2)
                o2[k2] = make_float2(ls[2 * k2], ls[2 * k2 + 1]);
            out[(size_t)B_N * K_N + b] = (float)bk;
            out[(size_t)B_N * K_N + B_N + b] = gcf;
        }
    }
}

// ---------------------------------------------------------------------------
extern "C" void kernel_launch(void* const* d_in, const int* in_sizes, int n_in,
                              void* d_out, int out_size, void* d_ws, size_t ws_size,
                              hipStream_t stream) {
    const float* data   = (const float*)d_in[0];   // [B, D]
    const float* mu     = (const float*)d_in[1];   // [C, D]
    const float* S      = (const float*)d_in[2];   // [C, D, D]
    const int*   onehot = (const int*)d_in[3];     // [C, K]
    float* out = (float*)d_out;

    // ws: QF [QF_N f16] | cls [C]
    _Float16* QF  = (_Float16*)d_ws;
    int*      cls = (int*)(QF + QF_N);

    hipLaunchKernelGGL(k_prep, dim3(C_N), dim3(128), 0, stream,
                       S, mu, onehot, QF, cls);
    hipLaunchKernelGGL(k_mainv8, dim3(B_N / 128), dim3(256), 0, stream,
                       data, QF, cls, out);
}

// Round 12
// 109.890 us; speedup vs baseline: 1.0486x; 1.0486x over previous
//
#include <hip/hip_runtime.h>
#include <cmath>

#define B_N 65536
#define C_N 128
#define D_N 32
#define K_N 10
#define EPS_F 1e-12f
#define SCALE_F (-0.72134752044448169f)   // -0.5 * log2(e)

#define NKK 48                    // 45 live K-steps + 3 zero pads (4-unroll)
#define CHUNK_F16 4096            // per-step Q chunk: 4ct x 2hl x 64lane x 8 f16 = 8 KB
#define QF_N (NKK * CHUNK_F16)
#define YSTR 33                   // y row stride; reads past col 32 hit neighbor data
                                  // but Q=0 there (e>32) so products are discarded

typedef _Float16 f16x8 __attribute__((ext_vector_type(8)));
typedef float    f32x16 __attribute__((ext_vector_type(16)));

// Step metadata, affine in (window w, row-pair r) order; kk>=45 zero-Q pad.
__device__ __forceinline__ void mdkk(int kk, int& dA, int& e0) {
    if (kk >= 45) { dA = 0; e0 = 0; return; }
    int w = (kk >= 17) + (kk >= 30) + (kk >= 39) + (kk >= 44);
    int off = w == 0 ? 0 : (w == 1 ? 17 : (w == 2 ? 30 : (w == 3 ? 39 : 44)));
    int r = kk - off;
    dA = 2 * r;
    e0 = 2 * r + 8 * w;
}

// ---------------------------------------------------------------------------
// Fused prep: block = cluster c; packs Q chunks (zeros for pad steps 45-47):
//   QF[kk*4096 + ct*1024 + hl*512 + (half*32 + (c&31))*8 + j]
// ---------------------------------------------------------------------------
__global__ __launch_bounds__(128) void k_prep(const float* __restrict__ S,
                                              const float* __restrict__ mu,
                                              const int* __restrict__ onehot,
                                              _Float16* __restrict__ QF,
                                              int* __restrict__ cls) {
    const int c = blockIdx.x;
    const int tid = threadIdx.x;
    __shared__ float sSm[D_N];
    __shared__ float st3;

    if (tid < D_N) {
        const float* Sr = S + (size_t)c * (D_N * D_N) + (size_t)tid * D_N;
        const float* mr = mu + (size_t)c * D_N;
        float a0 = 0.f, a1 = 0.f;
#pragma unroll
        for (int e = 0; e < D_N; e += 2) {
            a0 = fmaf(Sr[e + 0], mr[e + 0], a0);
            a1 = fmaf(Sr[e + 1], mr[e + 1], a1);
        }
        sSm[tid] = a0 + a1;
    }
    __syncthreads();
    if (tid == 0) {
        const float* mr = mu + (size_t)c * D_N;
        float a = 0.f;
#pragma unroll
        for (int d = 0; d < D_N; ++d) a = fmaf(mr[d], sSm[d], a);
        st3 = a;
        int cl = 0;
#pragma unroll
        for (int k = 0; k < K_N; ++k)
            if (onehot[c * K_N + k] != 0) cl = k;
        cls[c] = cl;
    }
    __syncthreads();

    if (tid < 2 * NKK) {
        const int kk   = tid >> 1;
        const int half = tid & 1;
        int dA, e0;
        mdkk(kk, dA, e0);
        const int d  = dA + half;
        const int ct = c >> 5;
        const size_t base = (size_t)kk * CHUNK_F16 + ct * 1024
                          + (size_t)(half * 32 + (c & 31)) * 8;
        const float* Sc = S + (size_t)c * (D_N * D_N);
        for (int j = 0; j < 8; ++j) {
            const int e = e0 + j;
            float q = 0.f;
            if (kk < 45 && d <= e && e <= 32) {
                float v;
                if (e < 32)      v = Sc[d * D_N + e] * (d == e ? 1.f : 2.f);
                else if (d < 32) v = -2.f * sSm[d];
                else             v = st3;          // d == e == 32
                q = SCALE_F * v;
            }
            _Float16 h = (_Float16)q;
            QF[base + j]       = h;                         // hi
            QF[base + 512 + j] = (_Float16)(q - (float)h);  // lo
        }
    }
}

// ---------------------------------------------------------------------------
// v9 helpers
// ---------------------------------------------------------------------------
__device__ __forceinline__ void gl_lds16(const void* g, void* l) {
    __builtin_amdgcn_global_load_lds(
        (const __attribute__((address_space(1))) unsigned int*)g,
        (__attribute__((address_space(3))) unsigned int*)l, 16, 0, 0);
}

__device__ __forceinline__ void stage_chunk(const _Float16* __restrict__ QF,
                                            _Float16* __restrict__ dst,
                                            int chunk, int wid, int lane) {
#pragma unroll
    for (int i = 0; i < 2; ++i) {
        const int slot = i * 4 + wid;
        gl_lds16(QF + (size_t)chunk * CHUNK_F16 + slot * 512 + lane * 8,
                 dst + slot * 512);
    }
}

__device__ __forceinline__ void ldy(const float* sy, int ybase, int hioff,
                                    int kk, float& yd, float (&yw)[8]) {
    int dA, e0;
    mdkk(kk, dA, e0);
    yd = sy[ybase + dA + hioff];
#pragma unroll
    for (int j = 0; j < 8; ++j) yw[j] = sy[ybase + e0 + j];
}

// phi build: cvt_pkrtz yields the packed 2xf16 dword directly; assemble the
// f16x8 via word copies (no element inserts -> minimal VALU).
__device__ __forceinline__ void mkphi(float yd, const float (&yw)[8],
                                      f16x8& ph, f16x8& pl) {
    union { unsigned int w[4]; f16x8 v; } H, L;
#pragma unroll
    for (int p = 0; p < 4; ++p) {
        float f0 = yd * yw[2 * p], f1 = yd * yw[2 * p + 1];
        auto h2 = __builtin_amdgcn_cvt_pkrtz(f0, f1);
        float r0 = f0 - (float)h2[0];
        float r1 = f1 - (float)h2[1];
        auto l2 = __builtin_amdgcn_cvt_pkrtz(r0, r1);
        __builtin_memcpy(&H.w[p], &h2, 4);
        __builtin_memcpy(&L.w[p], &l2, 4);
    }
    ph = H.v;
    pl = L.v;
}

// ---------------------------------------------------------------------------
// One pipelined phase (compile-time slots/parity; t runtime only for chunk
// index, guards, and y metadata). Per phase:
//   vmcnt(0)+barrier (own stage(t+1) landed; block-wide by barrier)
//   stage chunk t+2 -> slot SS          (global -> LDS, async)
//   ds_read Q(t+1) + y(t+1) -> regs[P^1] (LDS -> regs, overlaps MFMA below)
//   mkphi + 12 MFMA on step t from regs[P]
// Dependency chain of step t is entirely in registers -> LDS pipe, VALU and
// matrix pipe overlap within the wave (the v8 lesson: pipes were serialized).
// ---------------------------------------------------------------------------
template <int SN, int SS, int P>
__device__ __forceinline__ void phase_t(int t, const _Float16* __restrict__ QF,
                                        _Float16* __restrict__ qb,
                                        const float* __restrict__ sy,
                                        int ybase, int hioff, int wid, int lane,
                                        f16x8 (&qh)[2][4], f16x8 (&ql)[2][4],
                                        float (&yd)[2], float (&yw)[2][8],
                                        f32x16 (&acc)[4]) {
    asm volatile("s_waitcnt vmcnt(0)" ::: "memory");
    __builtin_amdgcn_s_barrier();
    __builtin_amdgcn_sched_barrier(0);
    if (t + 2 < NKK)
        stage_chunk(QF, qb + SS * CHUNK_F16, t + 2, wid, lane);
    if (t + 1 < NKK) {
        const f16x8* qn = (const f16x8*)(qb + SN * CHUNK_F16);
#pragma unroll
        for (int ct = 0; ct < 4; ++ct) {
            qh[P ^ 1][ct] = qn[ct * 128 + lane];
            ql[P ^ 1][ct] = qn[ct * 128 + 64 + lane];
        }
        ldy(sy, ybase, hioff, t + 1, yd[P ^ 1], yw[P ^ 1]);
    }
    f16x8 ph, pl;
    mkphi(yd[P], yw[P], ph, pl);
    __builtin_amdgcn_s_setprio(1);
#pragma unroll
    for (int ct = 0; ct < 4; ++ct)
        acc[ct] = __builtin_amdgcn_mfma_f32_32x32x16_f16(qh[P][ct], ph, acc[ct], 0, 0, 0);
#pragma unroll
    for (int ct = 0; ct < 4; ++ct)
        acc[ct] = __builtin_amdgcn_mfma_f32_32x32x16_f16(ql[P][ct], ph, acc[ct], 0, 0, 0);
#pragma unroll
    for (int ct = 0; ct < 4; ++ct)
        acc[ct] = __builtin_amdgcn_mfma_f32_32x32x16_f16(qh[P][ct], pl, acc[ct], 0, 0, 0);
    __builtin_amdgcn_s_setprio(0);
}

// ---------------------------------------------------------------------------
// Main v9: 32 rows/wave x 128 c x full K (v6 shape, register headroom),
// ring-4 LDS chunk buffer, stage distance 2, LDS->reg prefetch distance 1,
// 4x-unrolled loop (all slot/parity indices literal). Epilogue unchanged.
// ---------------------------------------------------------------------------
__global__ __launch_bounds__(256, 2) void k_mainv9(const float* __restrict__ data,
                                                   const _Float16* __restrict__ QF,
                                                   const int* __restrict__ clsp,
                                                   float* __restrict__ out) {
    const int tid  = threadIdx.x;
    const int lane = tid & 63;
    const int wid  = tid >> 6;
    const int b0w  = blockIdx.x * 128 + wid * 32;   // wave's first row
    const int col  = lane & 31;
    const bool hi  = lane >= 32;

    __shared__ float sy[256 * YSTR + 64];
    __shared__ alignas(16) _Float16 qb[4 * CHUNK_F16];
    __shared__ int lcls[C_N];
    if (tid < C_N) lcls[tid] = clsp[tid];

    const int ybase = tid * YSTR;
    {
        const float4* p0 = (const float4*)(data + (size_t)(b0w + col) * D_N);
#pragma unroll
        for (int i = 0; i < 8; ++i) {
            float4 v = p0[i];
            sy[ybase + 4 * i + 0] = v.x;
            sy[ybase + 4 * i + 1] = v.y;
            sy[ybase + 4 * i + 2] = v.z;
            sy[ybase + 4 * i + 3] = v.w;
        }
        sy[ybase + 32] = 1.f;                        // homogeneous slot
        if (tid < 64) sy[256 * YSTR + tid] = 0.f;    // tail pad
    }

    f32x16 acc[4];
#pragma unroll
    for (int ct = 0; ct < 4; ++ct)
#pragma unroll
        for (int g = 0; g < 16; ++g) acc[ct][g] = 0.f;

    // prologue: stage chunks 0,1; full drain once (covers sy too); then
    // prefetch step-0 operands into reg buffer 0.
    stage_chunk(QF, qb + 0 * CHUNK_F16, 0, wid, lane);
    stage_chunk(QF, qb + 1 * CHUNK_F16, 1, wid, lane);
    __syncthreads();

    const int hioff = hi ? 1 : 0;
    f16x8 qh[2][4], ql[2][4];
    float yd[2], yw[2][8];
    {
        const f16x8* q0 = (const f16x8*)qb;
#pragma unroll
        for (int ct = 0; ct < 4; ++ct) {
            qh[0][ct] = q0[ct * 128 + lane];
            ql[0][ct] = q0[ct * 128 + 64 + lane];
        }
        ldy(sy, ybase, hioff, 0, yd[0], yw[0]);
    }

#pragma clang loop unroll(disable)
    for (int t = 0; t < NKK; t += 4) {
        phase_t<1, 2, 0>(t + 0, QF, qb, sy, ybase, hioff, wid, lane, qh, ql, yd, yw, acc);
        phase_t<2, 3, 1>(t + 1, QF, qb, sy, ybase, hioff, wid, lane, qh, ql, yd, yw, acc);
        phase_t<3, 0, 0>(t + 2, QF, qb, sy, ybase, hioff, wid, lane, qh, ql, yd, yw, acc);
        phase_t<0, 1, 1>(t + 3, QF, qb, sy, ybase, hioff, wid, lane, qh, ql, yd, yw, acc);
    }

    // ---------------- fused finalize (Gamma stays in registers) --------------
    // C/D layout (HW-verified): col=lane&31 (b), c = ct*32+(g&3)+8*(g>>2)+4*hi
    const float hoff = hi ? 4.f : 0.f;
    const int* lc = lcls + (hi ? 4 : 0);
    float sum = 0.f, gmax = -1.f, gcf = 0.f;
    float a0 = 0, a1 = 0, a2 = 0, a3 = 0, a4 = 0, a5 = 0, a6 = 0, a7 = 0, a8 = 0, a9 = 0;
#pragma unroll
    for (int ct = 0; ct < 4; ++ct) {
        float psum = 0.f;
#pragma unroll
        for (int g = 0; g < 16; ++g) {
            float v = acc[ct][g];
            float gm;
            asm("v_exp_f32 %0, %1" : "=v"(gm) : "v"(v));   // 2^v = exp(-0.5 d2)
            const int cbase = ct * 32 + (g & 3) + 8 * (g >> 2);
            int cl = lc[cbase];
            psum += gm;
            float cf = (float)cbase + hoff;
            if (gm > gmax) { gmax = gm; gcf = cf; }        // c scanned ascending
            a0 += (cl == 0) ? gm : 0.f;
            a1 += (cl == 1) ? gm : 0.f;
            a2 += (cl == 2) ? gm : 0.f;
            a3 += (cl == 3) ? gm : 0.f;
            a4 += (cl == 4) ? gm : 0.f;
            a5 += (cl == 5) ? gm : 0.f;
            a6 += (cl == 6) ? gm : 0.f;
            a7 += (cl == 7) ? gm : 0.f;
            a8 += (cl == 8) ? gm : 0.f;
            a9 += (cl == 9) ? gm : 0.f;
        }
        sum += psum;
    }

    sum += __shfl_xor(sum, 32, 64);
    {
        float om = __shfl_xor(gmax, 32, 64);
        float oc = __shfl_xor(gcf, 32, 64);
        bool take = (om > gmax) || (om == gmax && oc < gcf);  // first-index tie
        if (take) { gmax = om; gcf = oc; }
    }
    a0 += __shfl_xor(a0, 32, 64);
    a1 += __shfl_xor(a1, 32, 64);
    a2 += __shfl_xor(a2, 32, 64);
    a3 += __shfl_xor(a3, 32, 64);
    a4 += __shfl_xor(a4, 32, 64);
    a5 += __shfl_xor(a5, 32, 64);
    a6 += __shfl_xor(a6, 32, 64);
    a7 += __shfl_xor(a7, 32, 64);
    a8 += __shfl_xor(a8, 32, 64);
    a9 += __shfl_xor(a9, 32, 64);

    if (!hi) {
        const int b = b0w + col;
        float inv = 1.0f / (sum + EPS_F);
        float ls[K_N] = {a0 * inv, a1 * inv, a2 * inv, a3 * inv, a4 * inv,
                         a5 * inv, a6 * inv, a7 * inv, a8 * inv, a9 * inv};
        float best = -1.f;
        int bk = 0;
#pragma unroll
        for (int k = 0; k < K_N; ++k)
            if (ls[k] > best) { best = ls[k]; bk = k; }
        float2* o2 = (float2*)(out + (size_t)b * K_N);   // b*40B is 8B-aligned
#pragma unroll
        for (int k2 = 0; k2 < K_N / 2; ++k2)
            o2[k2] = make_float2(ls[2 * k2], ls[2 * k2 + 1]);
        out[(size_t)B_N * K_N + b] = (float)bk;
        out[(size_t)B_N * K_N + B_N + b] = gcf;
    }
}

// ---------------------------------------------------------------------------
extern "C" void kernel_launch(void* const* d_in, const int* in_sizes, int n_in,
                              void* d_out, int out_size, void* d_ws, size_t ws_size,
                              hipStream_t stream) {
    const float* data   = (const float*)d_in[0];   // [B, D]
    const float* mu     = (const float*)d_in[1];   // [C, D]
    const float* S      = (const float*)d_in[2];   // [C, D, D]
    const int*   onehot = (const int*)d_in[3];     // [C, K]
    float* out = (float*)d_out;

    // ws: QF [QF_N f16] | cls [C]
    _Float16* QF  = (_Float16*)d_ws;
    int*      cls = (int*)(QF + QF_N);

    hipLaunchKernelGGL(k_prep, dim3(C_N), dim3(128), 0, stream,
                       S, mu, onehot, QF, cls);
    hipLaunchKernelGGL(k_mainv9, dim3(B_N / 128), dim3(256), 0, stream,
                       data, QF, cls, out);
}